// Round 1
// baseline (179.458 us; speedup 1.0000x reference)
//
#include <hip/hip_runtime.h>
#include <math.h>

#define NTILES 64
#define TPC 8
#define NCLUST 8
#define GRID_SZ 16
#define DIM 512
#define DHID 128
#define NTOK 2048
#define LN_EPS 1e-5f
#define CH 4
#define MAXJ 64

static __device__ __forceinline__ float fsign(float v) {
    return (v > 0.f) ? 1.f : ((v < 0.f) ? -1.f : 0.f);
}

// tile_sigs[t*DIM+d] = sign(mean over dh of Wd[t][dh][d])
__global__ __launch_bounds__(256) void k_tile_sigs(const float* __restrict__ Wd,
                                                   float* __restrict__ tile_sigs) {
    int i = blockIdx.x * blockDim.x + threadIdx.x;
    if (i >= NTILES * DIM) return;
    int t = i >> 9;          // /DIM
    int d = i & (DIM - 1);
    const float* p = Wd + (size_t)t * DHID * DIM + d;
    float s = 0.f;
    #pragma unroll 4
    for (int dh = 0; dh < DHID; ++dh) s += p[(size_t)dh * DIM];
    tile_sigs[i] = fsign(s);
}

// cluster_sigs[c*DIM+d] = sign(mean over TPC of tile_sigs); also zero counts
__global__ __launch_bounds__(256) void k_cluster_sigs(const float* __restrict__ tile_sigs,
                                                      float* __restrict__ cluster_sigs,
                                                      int* __restrict__ counts) {
    int i = blockIdx.x * blockDim.x + threadIdx.x;
    if (i < NTILES) counts[i] = 0;
    if (i >= NCLUST * DIM) return;
    int c = i >> 9;
    int d = i & (DIM - 1);
    float s = 0.f;
    #pragma unroll
    for (int k = 0; k < TPC; ++k) s += tile_sigs[(size_t)(c * TPC + k) * DIM + d];
    cluster_sigs[i] = fsign(s);
}

// one wave (64 lanes) per token: LayerNorm + routing + list build
__global__ __launch_bounds__(64) void k_ln_route(const float* __restrict__ x,
                                                 const float* __restrict__ gamma,
                                                 const float* __restrict__ beta,
                                                 const float* __restrict__ tile_sigs,
                                                 const float* __restrict__ cluster_sigs,
                                                 float* __restrict__ xn_out,
                                                 int* __restrict__ counts,
                                                 int* __restrict__ list) {
    int n = blockIdx.x;
    int lane = threadIdx.x;
    const float* xr = x + (size_t)n * DIM;

    float v[8];
    float sum = 0.f;
    #pragma unroll
    for (int j = 0; j < 8; ++j) { float t = xr[lane + 64 * j]; v[j] = t; sum += t; }
    #pragma unroll
    for (int off = 32; off; off >>= 1) sum += __shfl_xor(sum, off);
    float mu = sum * (1.f / DIM);

    float sq = 0.f;
    #pragma unroll
    for (int j = 0; j < 8; ++j) { float t = v[j] - mu; sq += t * t; }
    #pragma unroll
    for (int off = 32; off; off >>= 1) sq += __shfl_xor(sq, off);
    float rs = rsqrtf(sq * (1.f / DIM) + LN_EPS);

    float sg[8];
    #pragma unroll
    for (int j = 0; j < 8; ++j) {
        int d = lane + 64 * j;
        float xv = (v[j] - mu) * rs * gamma[d] + beta[d];
        xn_out[(size_t)n * DIM + d] = xv;
        sg[j] = fsign(xv);
    }

    // cluster argmax (scores are exact integers in f32; strict > ascending = first-index tie-break)
    int best_c = 0; float best = -1e30f;
    for (int c = 0; c < NCLUST; ++c) {
        float s = 0.f;
        #pragma unroll
        for (int j = 0; j < 8; ++j) s += sg[j] * cluster_sigs[(size_t)c * DIM + lane + 64 * j];
        #pragma unroll
        for (int off = 32; off; off >>= 1) s += __shfl_xor(s, off);
        if (s > best) { best = s; best_c = c; }
    }
    // local tile argmax within best cluster
    int bt = best_c * TPC; float bts = -1e30f;
    for (int k = 0; k < TPC; ++k) {
        int t = best_c * TPC + k;
        float s = 0.f;
        #pragma unroll
        for (int j = 0; j < 8; ++j) s += sg[j] * tile_sigs[(size_t)t * DIM + lane + 64 * j];
        #pragma unroll
        for (int off = 32; off; off >>= 1) s += __shfl_xor(s, off);
        if (s > bts) { bts = s; bt = t; }
    }

    if (lane == 0) {
        int slot = atomicAdd(&counts[bt], 1);
        list[(size_t)bt * NTOK + slot] = n;
    }
}

// grid (tile, chunk): each block does CH tokens of one tile: down-GEMV, spline, up-GEMV, residual
__global__ __launch_bounds__(256) void k_ffn(const float* __restrict__ x,
                                             const float* __restrict__ xn,
                                             const float* __restrict__ Wd,
                                             const float* __restrict__ sb,
                                             const float* __restrict__ ss,
                                             const float* __restrict__ Wu,
                                             const float* __restrict__ scale,
                                             const int* __restrict__ counts,
                                             const int* __restrict__ list,
                                             float* __restrict__ out) {
    int t = blockIdx.x;
    int cnt = counts[t];
    if ((int)blockIdx.y * CH >= cnt) return;

    __shared__ float xn_s[2][DIM];
    __shared__ float hs_s[CH][DHID];
    __shared__ int toks[CH];

    float sc_t = scale[t];
    const float* Wdt = Wd + (size_t)t * DHID * DIM;
    const float* Wut = Wu + (size_t)t * DIM * DHID;
    const float* sbt = sb + (size_t)t * DHID * GRID_SZ;
    const float* sst = ss + (size_t)t * DHID * GRID_SZ;
    int tid = threadIdx.x;

    for (int j0 = blockIdx.y; j0 * CH < cnt; j0 += MAXJ) {
        int base = j0 * CH;
        int m = min(CH, cnt - base);
        if (tid < CH) toks[tid] = (tid < m) ? list[(size_t)t * NTOK + base + tid] : -1;
        __syncthreads();

        // down-projection + spline, two tokens at a time
        for (int p = 0; p < CH; p += 2) {
            #pragma unroll
            for (int pp = 0; pp < 2; ++pp) {
                int tok = toks[p + pp];  // valid read: toks filled to CH with -1
                if (p + pp < m && tok >= 0) {
                    for (int d = tid; d < DIM; d += 256)
                        xn_s[pp][d] = xn[(size_t)tok * DIM + d];
                }
            }
            __syncthreads();
            int pp = tid >> 7;
            int dh = tid & (DHID - 1);
            if (p + pp < m) {
                const float* wr = Wdt + (size_t)dh * DIM;
                float4 a = {0.f, 0.f, 0.f, 0.f};
                for (int d = 0; d < DIM; d += 4) {
                    float4 w = *(const float4*)(wr + d);
                    float4 xv = *(const float4*)(&xn_s[pp][d]);
                    a.x += w.x * xv.x; a.y += w.y * xv.y;
                    a.z += w.z * xv.z; a.w += w.w * xv.w;
                }
                float h = (a.x + a.y) + (a.z + a.w);
                float hn = 1.f / (1.f + expf(-h));
                float g = hn * (float)GRID_SZ;
                int idx = (int)g;                 // trunc == floor (hn >= 0)
                idx = (idx > GRID_SZ - 1) ? GRID_SZ - 1 : (idx < 0 ? 0 : idx);
                float lp = g - (float)idx;
                float bse = sbt[dh * GRID_SZ + idx];
                float slp = sst[dh * GRID_SZ + idx];
                hs_s[p + pp][dh] = bse + slp * lp;
            }
            __syncthreads();
        }

        // up-projection + scale + residual, one token at a time
        for (int p = 0; p < m; ++p) {
            int tok = toks[p];
            #pragma unroll
            for (int dd = 0; dd < 2; ++dd) {
                int d = tid + dd * 256;
                const float* wr = Wut + (size_t)d * DHID;
                float4 a = {0.f, 0.f, 0.f, 0.f};
                for (int dh = 0; dh < DHID; dh += 4) {
                    float4 w = *(const float4*)(wr + dh);
                    a.x += w.x * hs_s[p][dh];
                    a.y += w.y * hs_s[p][dh + 1];
                    a.z += w.z * hs_s[p][dh + 2];
                    a.w += w.w * hs_s[p][dh + 3];
                }
                float y = ((a.x + a.y) + (a.z + a.w)) * sc_t;
                out[(size_t)tok * DIM + d] = x[(size_t)tok * DIM + d] + y;
            }
        }
        __syncthreads();
    }
}

extern "C" void kernel_launch(void* const* d_in, const int* in_sizes, int n_in,
                              void* d_out, int out_size, void* d_ws, size_t ws_size,
                              hipStream_t stream) {
    const float* x     = (const float*)d_in[0];
    const float* gamma = (const float*)d_in[1];
    const float* beta  = (const float*)d_in[2];
    const float* Wd    = (const float*)d_in[3];
    const float* sb    = (const float*)d_in[4];
    const float* ss    = (const float*)d_in[5];
    const float* Wu    = (const float*)d_in[6];
    const float* scale = (const float*)d_in[7];
    float* out = (float*)d_out;

    // workspace layout
    float* tile_sigs    = (float*)d_ws;                          // T*D     = 32768 f
    float* cluster_sigs = tile_sigs + NTILES * DIM;              // C*D     = 4096 f
    float* xn           = cluster_sigs + NCLUST * DIM;           // N*D     = 1048576 f
    int*   counts       = (int*)(xn + (size_t)NTOK * DIM);       // T ints
    int*   list         = counts + NTILES;                       // T*N ints

    k_tile_sigs<<<(NTILES * DIM + 255) / 256, 256, 0, stream>>>(Wd, tile_sigs);
    k_cluster_sigs<<<(NCLUST * DIM + 255) / 256, 256, 0, stream>>>(tile_sigs, cluster_sigs, counts);
    k_ln_route<<<NTOK, 64, 0, stream>>>(x, gamma, beta, tile_sigs, cluster_sigs, xn, counts, list);
    k_ffn<<<dim3(NTILES, MAXJ), 256, 0, stream>>>(x, xn, Wd, sb, ss, Wu, scale, counts, list, out);
}

// Round 2
// 65.603 us; speedup vs baseline: 2.7355x; 2.7355x over previous
//
#include <hip/hip_runtime.h>
#include <math.h>

#define NTILES 64
#define TPC 8
#define NCLUST 8
#define GRID_SZ 16
#define DIM 512
#define DHID 128
#define NTOK 2048
#define LN_EPS 1e-5f
#define TB 8          // tokens per k_ffn block
#define MAXCH 32      // grid.y chunks for k_ffn

static __device__ __forceinline__ float fsign(float v) {
    return (v > 0.f) ? 1.f : ((v < 0.f) ? -1.f : 0.f);
}

// Stage 1 of tile signatures: partial sums over 16 dh each.
// grid (NTILES, 8), 256 threads. Also zeros counts.
__global__ __launch_bounds__(256) void k_sig_part(const float* __restrict__ Wd,
                                                  float* __restrict__ psum,
                                                  int* __restrict__ counts) {
    int t = blockIdx.x, part = blockIdx.y, tid = threadIdx.x;
    if (t == 0 && part == 0 && tid < NTILES) counts[tid] = 0;
    const float* base = Wd + ((size_t)t * DHID + part * 16) * DIM;
    #pragma unroll
    for (int k = 0; k < 2; ++k) {
        int d = tid + k * 256;
        float s = 0.f;
        #pragma unroll
        for (int j = 0; j < 16; ++j) s += base[(size_t)j * DIM + d];
        psum[((size_t)t * 8 + part) * DIM + d] = s;
    }
}

// Stage 2: tile_sigs + cluster_sigs. grid (NCLUST, 2), 256 threads.
__global__ __launch_bounds__(256) void k_sigs(const float* __restrict__ psum,
                                              float* __restrict__ tile_sigs,
                                              float* __restrict__ cluster_sigs) {
    int c = blockIdx.x;
    int d = blockIdx.y * 256 + threadIdx.x;
    float csum = 0.f;
    #pragma unroll
    for (int k = 0; k < TPC; ++k) {
        int t = c * TPC + k;
        float s = 0.f;
        #pragma unroll
        for (int p = 0; p < 8; ++p) s += psum[((size_t)t * 8 + p) * DIM + d];
        float sg = fsign(s);
        tile_sigs[(size_t)t * DIM + d] = sg;
        csum += sg;
    }
    cluster_sigs[(size_t)c * DIM + d] = fsign(csum);
}

// one wave (64 lanes) per token: LayerNorm + routing + list build
__global__ __launch_bounds__(64) void k_ln_route(const float* __restrict__ x,
                                                 const float* __restrict__ gamma,
                                                 const float* __restrict__ beta,
                                                 const float* __restrict__ tile_sigs,
                                                 const float* __restrict__ cluster_sigs,
                                                 float* __restrict__ xn_out,
                                                 int* __restrict__ counts,
                                                 int* __restrict__ list) {
    int n = blockIdx.x;
    int lane = threadIdx.x;
    const float* xr = x + (size_t)n * DIM;

    float v[8];
    float sum = 0.f;
    #pragma unroll
    for (int j = 0; j < 8; ++j) { float t = xr[lane + 64 * j]; v[j] = t; sum += t; }
    #pragma unroll
    for (int off = 32; off; off >>= 1) sum += __shfl_xor(sum, off);
    float mu = sum * (1.f / DIM);

    float sq = 0.f;
    #pragma unroll
    for (int j = 0; j < 8; ++j) { float t = v[j] - mu; sq += t * t; }
    #pragma unroll
    for (int off = 32; off; off >>= 1) sq += __shfl_xor(sq, off);
    float rs = rsqrtf(sq * (1.f / DIM) + LN_EPS);

    float sg[8];
    #pragma unroll
    for (int j = 0; j < 8; ++j) {
        int d = lane + 64 * j;
        float xv = (v[j] - mu) * rs * gamma[d] + beta[d];
        xn_out[(size_t)n * DIM + d] = xv;
        sg[j] = fsign(xv);
    }

    // cluster argmax (scores exact integers in f32; strict > ascending = first-index tie-break)
    int best_c = 0; float best = -1e30f;
    for (int c = 0; c < NCLUST; ++c) {
        float s = 0.f;
        #pragma unroll
        for (int j = 0; j < 8; ++j) s += sg[j] * cluster_sigs[(size_t)c * DIM + lane + 64 * j];
        #pragma unroll
        for (int off = 32; off; off >>= 1) s += __shfl_xor(s, off);
        if (s > best) { best = s; best_c = c; }
    }
    int bt = best_c * TPC; float bts = -1e30f;
    for (int k = 0; k < TPC; ++k) {
        int t = best_c * TPC + k;
        float s = 0.f;
        #pragma unroll
        for (int j = 0; j < 8; ++j) s += sg[j] * tile_sigs[(size_t)t * DIM + lane + 64 * j];
        #pragma unroll
        for (int off = 32; off; off >>= 1) s += __shfl_xor(s, off);
        if (s > bts) { bts = s; bt = t; }
    }

    if (lane == 0) {
        int slot = atomicAdd(&counts[bt], 1);
        list[(size_t)bt * NTOK + slot] = n;
    }
}

// grid (tile, chunk): 512 threads, TB=8 tokens per chunk.
// down: thread=(dh, quarter-of-d), 8-token register blocking (32 FMA per weight float4)
// up:   thread=d, 8-token register blocking, coalesced residual+store
__global__ __launch_bounds__(512) void k_ffn(const float* __restrict__ x,
                                             const float* __restrict__ xn,
                                             const float* __restrict__ Wd,
                                             const float* __restrict__ sb,
                                             const float* __restrict__ ss,
                                             const float* __restrict__ Wu,
                                             const float* __restrict__ scale,
                                             const int* __restrict__ counts,
                                             const int* __restrict__ list,
                                             float* __restrict__ out) {
    int t = blockIdx.x;
    int cnt = counts[t];
    if ((int)blockIdx.y * TB >= cnt) return;

    __shared__ float xn_s[TB][DIM];        // 16 KB
    __shared__ float hp_s[4][TB][DHID];    // 16 KB
    __shared__ float hs_s[TB][DHID];       // 4 KB
    __shared__ int toks[TB];

    int tid = threadIdx.x;
    float sc_t = scale[t];
    const float* sbt = sb + (size_t)t * DHID * GRID_SZ;
    const float* sst = ss + (size_t)t * DHID * GRID_SZ;
    int dh = tid & (DHID - 1);
    int q  = tid >> 7;                     // 0..3 quarter of d
    const float* wd = Wd + ((size_t)t * DHID + dh) * DIM + q * 128;
    const float* wu = Wu + ((size_t)t * DIM + tid) * DHID;

    for (int j0 = blockIdx.y; j0 * TB < cnt; j0 += MAXCH) {
        int base = j0 * TB;
        int m = min(TB, cnt - base);
        if (tid < TB) toks[tid] = (tid < m) ? list[(size_t)t * NTOK + base + tid] : -1;
        __syncthreads();

        // stage xn for TB tokens (zeros for padding), coalesced float4
        #pragma unroll
        for (int k = 0; k < 2; ++k) {
            int f = tid + k * 512;         // 1024 float4 = TB*DIM/4
            int p = f >> 7;
            int d4 = (f & 127) * 4;
            float4 v = {0.f, 0.f, 0.f, 0.f};
            int tok = toks[p];
            if (tok >= 0) v = *(const float4*)(xn + (size_t)tok * DIM + d4);
            *(float4*)(&xn_s[p][d4]) = v;
        }
        __syncthreads();

        // down-projection: each thread reduces 128 d for its dh, all 8 tokens
        float acc[TB];
        #pragma unroll
        for (int p = 0; p < TB; ++p) acc[p] = 0.f;
        #pragma unroll 4
        for (int it = 0; it < 32; ++it) {
            float4 w = *(const float4*)(wd + it * 4);
            int d = q * 128 + it * 4;
            #pragma unroll
            for (int p = 0; p < TB; ++p) {
                float4 xv = *(const float4*)(&xn_s[p][d]);
                acc[p] += w.x * xv.x + w.y * xv.y + w.z * xv.z + w.w * xv.w;
            }
        }
        #pragma unroll
        for (int p = 0; p < TB; ++p) hp_s[q][p][dh] = acc[p];
        __syncthreads();

        // combine quarters + spline (TB*DHID = 1024 elems, 2 per thread)
        #pragma unroll
        for (int k = 0; k < 2; ++k) {
            int e = tid + k * 512;
            int p = e >> 7, dd = e & 127;
            float h = hp_s[0][p][dd] + hp_s[1][p][dd] + hp_s[2][p][dd] + hp_s[3][p][dd];
            float hn = 1.f / (1.f + expf(-h));
            float g = hn * (float)GRID_SZ;
            int idx = (int)g;
            idx = (idx > GRID_SZ - 1) ? GRID_SZ - 1 : (idx < 0 ? 0 : idx);
            float lp = g - (float)idx;
            hs_s[p][dd] = sbt[dd * GRID_SZ + idx] + sst[dd * GRID_SZ + idx] * lp;
        }
        __syncthreads();

        // up-projection: thread owns output d = tid, reduce over 128 dh, all 8 tokens
        float acu[TB];
        #pragma unroll
        for (int p = 0; p < TB; ++p) acu[p] = 0.f;
        #pragma unroll 4
        for (int it = 0; it < 32; ++it) {
            float4 w = *(const float4*)(wu + it * 4);
            #pragma unroll
            for (int p = 0; p < TB; ++p) {
                float4 hv = *(const float4*)(&hs_s[p][it * 4]);
                acu[p] += w.x * hv.x + w.y * hv.y + w.z * hv.z + w.w * hv.w;
            }
        }
        for (int p = 0; p < m; ++p) {
            int tok = toks[p];
            out[(size_t)tok * DIM + tid] = x[(size_t)tok * DIM + tid] + acu[p] * sc_t;
        }
        __syncthreads();
    }
}

extern "C" void kernel_launch(void* const* d_in, const int* in_sizes, int n_in,
                              void* d_out, int out_size, void* d_ws, size_t ws_size,
                              hipStream_t stream) {
    const float* x     = (const float*)d_in[0];
    const float* gamma = (const float*)d_in[1];
    const float* beta  = (const float*)d_in[2];
    const float* Wd    = (const float*)d_in[3];
    const float* sb    = (const float*)d_in[4];
    const float* ss    = (const float*)d_in[5];
    const float* Wu    = (const float*)d_in[6];
    const float* scale = (const float*)d_in[7];
    float* out = (float*)d_out;

    // workspace layout
    float* psum         = (float*)d_ws;                          // 64*8*512 = 256K f (1 MB)
    float* tile_sigs    = psum + (size_t)NTILES * 8 * DIM;       // 32K f
    float* cluster_sigs = tile_sigs + NTILES * DIM;              // 4K f
    float* xn           = cluster_sigs + NCLUST * DIM;           // 1M f (4 MB)
    int*   counts       = (int*)(xn + (size_t)NTOK * DIM);       // 64 ints
    int*   list         = counts + NTILES;                       // 128K ints

    k_sig_part<<<dim3(NTILES, 8), 256, 0, stream>>>(Wd, psum, counts);
    k_sigs<<<dim3(NCLUST, 2), 256, 0, stream>>>(psum, tile_sigs, cluster_sigs);
    k_ln_route<<<NTOK, 64, 0, stream>>>(x, gamma, beta, tile_sigs, cluster_sigs, xn, counts, list);
    k_ffn<<<dim3(NTILES, MAXCH), 512, 0, stream>>>(x, xn, Wd, sb, ss, Wu, scale, counts, list, out);
}